// Round 9
// baseline (170.473 us; speedup 1.0000x reference)
//
#include <hip/hip_runtime.h>
#include <hip/hip_bf16.h>
#include <math.h>

typedef unsigned short u16;
typedef __attribute__((ext_vector_type(8))) short short8;
typedef __attribute__((ext_vector_type(4))) float float4v;
typedef __attribute__((ext_vector_type(4))) u16 ushort4v;

namespace {
constexpr int kT    = 2048;
constexpr int kDim  = 1024;
constexpr int kH    = 16;
constexpr int kHKV  = 4;
constexpr int kD    = 64;
constexpr int kTok  = 4096;   // B*T
}

__device__ __forceinline__ u16 f2bf(float f) {
  unsigned int u = __builtin_bit_cast(unsigned int, f);
  u = (u + 0x7FFFu + ((u >> 16) & 1u)) >> 16;   // RNE
  return (u16)u;
}
__device__ __forceinline__ unsigned pk2(float a, float b) {
  __hip_bfloat162 h = __float22bfloat162_rn(make_float2(a, b));  // v_cvt_pk_bf16_f32
  unsigned u; __builtin_memcpy(&u, &h, 4);
  return u;
}
__device__ __forceinline__ uint2 pack4(float a, float b, float c, float d) {
  return make_uint2(pk2(a, b), pk2(c, d));
}

// ---------------- fused prep: rope table + x->bf16 + 4x fake-quant -----------
// blocks [0,128): rope table; [128,2176): cvt x; [2176,4736): quant rows.
__global__ __launch_bounds__(256) void prep_kernel(
    const float* __restrict__ x,
    const float* __restrict__ w_q, const float* __restrict__ w_k,
    const float* __restrict__ w_v, const float* __restrict__ w_proj,
    u16* __restrict__ xb, u16* __restrict__ wqkv, u16* __restrict__ wpq,
    float2* __restrict__ ropetab)
{
  __shared__ float red[4];
  const int bid = blockIdx.x, tid = threadIdx.x;

  if (bid < 128) {                       // rope table (bitwise-same transcendentals)
    const int idx = bid * 256 + tid;     // 0..32767
    const int t = idx >> 4, i = idx & 15;
    const float fr = (float)t * powf(10000.0f, -(float)i * (1.0f / 16.0f));
    ropetab[idx] = make_float2(cosf(fr), sinf(fr));
    return;
  }
  if (bid < 2176) {                      // x -> bf16, 8 elems/thread
    const size_t i = ((size_t)(bid - 128) * 256 + tid) * 8;
    const float4 a = *(const float4*)(x + i);
    const float4 b = *(const float4*)(x + i + 4);
    short8 r;
    r[0] = (short)f2bf(a.x); r[1] = (short)f2bf(a.y);
    r[2] = (short)f2bf(a.z); r[3] = (short)f2bf(a.w);
    r[4] = (short)f2bf(b.x); r[5] = (short)f2bf(b.y);
    r[6] = (short)f2bf(b.z); r[7] = (short)f2bf(b.w);
    *(short8*)(xb + i) = r;
    return;
  }
  // fake-quant: one block per weight row (1024 cols, 4/thread, register-held)
  const int rid = bid - 2176;            // 0..2559
  const float* src; u16* dst; float halfv;
  if (rid < 1024)      { src = w_q    + (size_t)rid * 1024;          dst = wqkv + (size_t)rid * 1024;          halfv = 32.0f; }
  else if (rid < 1280) { src = w_k    + (size_t)(rid - 1024) * 1024; dst = wqkv + (size_t)rid * 1024;          halfv = 32.0f; }
  else if (rid < 1536) { src = w_v    + (size_t)(rid - 1280) * 1024; dst = wqkv + (size_t)rid * 1024;          halfv = 16.0f; }
  else                 { src = w_proj + (size_t)(rid - 1536) * 1024; dst = wpq  + (size_t)(rid - 1536) * 1024; halfv = 16.0f; }

  const float4 v4 = *(const float4*)(src + tid * 4);
  float mx = fmaxf(fmaxf(fabsf(v4.x), fabsf(v4.y)), fmaxf(fabsf(v4.z), fabsf(v4.w)));
  #pragma unroll
  for (int m = 1; m < 64; m <<= 1) mx = fmaxf(mx, __shfl_xor(mx, m));
  if ((tid & 63) == 0) red[tid >> 6] = mx;
  __syncthreads();
  mx = fmaxf(fmaxf(red[0], red[1]), fmaxf(red[2], red[3]));
  const float wmax = fmaxf(mx, 1e-5f);
  const float inv_half = 1.0f / halfv;
  const float vals[4] = {v4.x, v4.y, v4.z, v4.w};
  ushort4v o;
  #pragma unroll
  for (int j = 0; j < 4; ++j) {
    float r = rintf(vals[j] / wmax * halfv);
    r = fminf(fmaxf(r, -halfv), halfv - 1.0f);
    o[j] = f2bf(r * inv_half * wmax);
  }
  *(ushort4v*)(dst + tid * 4) = o;
}

// ======== 128x128 bf16 MFMA GEMM core (2x2 waves of 64x64, BK=32) ============
// 16 MFMA / 8 ds_read_b128 per wave per K-step; register prefetch over barrier.
// acc[mi][ni][i]: row = m0+wm+mi*16+quad*4+i, col = n0+wn+ni*16+n.
#define GEMM128_CORE(A_, W_, K_)                                               \
  __shared__ u16 As[128][32];                                                  \
  __shared__ u16 Bs[128][32];                                                  \
  const int tid = threadIdx.x;                                                 \
  const int lane = tid & 63, wv = tid >> 6;                                    \
  const int n = lane & 15, quad = lane >> 4;                                   \
  const int wm = (wv & 1) * 64, wn = (wv >> 1) * 64;                           \
  const int m0 = blockIdx.y * 128, n0 = blockIdx.x * 128;                      \
  const int sr = tid >> 2, sc = (tid & 3) * 8;                                 \
  const int scs = sc ^ ((sr & 3) * 8);                                         \
  float4v acc[4][4];                                                           \
  _Pragma("unroll")                                                            \
  for (int mi = 0; mi < 4; ++mi)                                               \
    _Pragma("unroll")                                                          \
    for (int ni = 0; ni < 4; ++ni) {                                           \
      acc[mi][ni][0]=0.f; acc[mi][ni][1]=0.f;                                  \
      acc[mi][ni][2]=0.f; acc[mi][ni][3]=0.f; }                                \
  short8 a0r, a1r, b0r, b1r;                                                   \
  a0r = *(const short8*)(A_ + (size_t)(m0 + sr) * K_ + sc);                    \
  a1r = *(const short8*)(A_ + (size_t)(m0 + sr + 64) * K_ + sc);               \
  b0r = *(const short8*)(W_ + (size_t)(n0 + sr) * K_ + sc);                    \
  b1r = *(const short8*)(W_ + (size_t)(n0 + sr + 64) * K_ + sc);               \
  for (int k0 = 0; k0 < K_; k0 += 32) {                                        \
    __syncthreads();                                                           \
    *(short8*)&As[sr][scs] = a0r;  *(short8*)&As[sr + 64][scs] = a1r;          \
    *(short8*)&Bs[sr][scs] = b0r;  *(short8*)&Bs[sr + 64][scs] = b1r;          \
    __syncthreads();                                                           \
    if (k0 + 32 < K_) {                                                        \
      a0r = *(const short8*)(A_ + (size_t)(m0 + sr) * K_ + k0 + 32 + sc);      \
      a1r = *(const short8*)(A_ + (size_t)(m0 + sr + 64) * K_ + k0 + 32 + sc); \
      b0r = *(const short8*)(W_ + (size_t)(n0 + sr) * K_ + k0 + 32 + sc);      \
      b1r = *(const short8*)(W_ + (size_t)(n0 + sr + 64) * K_ + k0 + 32 + sc); \
    }                                                                          \
    short8 af[4], bfr[4];                                                      \
    _Pragma("unroll")                                                          \
    for (int mi = 0; mi < 4; ++mi)                                             \
      af[mi] = *(const short8*)&As[wm + mi * 16 + n][(quad * 8) ^ ((n & 3) * 8)]; \
    _Pragma("unroll")                                                          \
    for (int ni = 0; ni < 4; ++ni)                                             \
      bfr[ni] = *(const short8*)&Bs[wn + ni * 16 + n][(quad * 8) ^ ((n & 3) * 8)]; \
    _Pragma("unroll")                                                          \
    for (int mi = 0; mi < 4; ++mi)                                             \
      _Pragma("unroll")                                                        \
      for (int ni = 0; ni < 4; ++ni)                                           \
        acc[mi][ni] = __builtin_amdgcn_mfma_f32_16x16x32_bf16(af[mi], bfr[ni], acc[mi][ni], 0, 0, 0); \
  }

// -------- QKV GEMM with fused RMSNorm+RoPE+gain epilogue ---------------------
// Each wave's 64-col half-panel = one head: hcol = (n0+wn)/64 in 0..23.
// 0..15 q head, 16..19 k head, 20..23 v head (V^T bf16 + compact fp32 v).
__global__ __launch_bounds__(256) void gemm_qkv(
    const u16* __restrict__ A, const u16* __restrict__ W,
    const float2* __restrict__ ropetab, const float* __restrict__ q_gain,
    u16* __restrict__ qh, u16* __restrict__ kh,
    u16* __restrict__ vT, float* __restrict__ vcmp)
{
  GEMM128_CORE(A, W, kDim)

  const int hcol = (n0 + wn) >> 6;           // head/panel id 0..23
  const int rbase = m0 + wm;                 // + mi*16 + quad*4 + i = token row
  const int bI = rbase >> 11;                // batch (128-row tiles never straddle)

  if (hcol < 20) {
    // q (head hcol) or k (head hcol-16): RMSNorm over 64 dims + RoPE + gain
    const float gain = (hcol < 16) ? q_gain[hcol] * 0.125f : 1.0f;
    u16* dst = (hcol < 16) ? qh + ((size_t)(bI * kH + hcol) * kT) * kD
                           : kh + ((size_t)(bI * kHKV + (hcol - 16)) * kT) * kD;
    #pragma unroll
    for (int mi = 0; mi < 4; ++mi)
      #pragma unroll
      for (int i = 0; i < 4; ++i) {
        const int row = rbase + mi * 16 + quad * 4 + i;
        const int t = row & (kT - 1);
        float v[4];
        #pragma unroll
        for (int ni = 0; ni < 4; ++ni) v[ni] = acc[mi][ni][i];
        float ss = v[0]*v[0] + v[1]*v[1] + v[2]*v[2] + v[3]*v[3];
        #pragma unroll
        for (int m = 1; m < 16; m <<= 1) ss += __shfl_xor(ss, m);
        const float rr = 1.0f / sqrtf(ss * (1.0f / 64.0f) + 1.1920929e-7f);
        #pragma unroll
        for (int ni = 0; ni < 4; ++ni) v[ni] *= rr;
        const float2 cs = ropetab[t * 16 + n];
        const float r0 =  v[0] * cs.x + v[1] * cs.y;
        const float r1 = -v[0] * cs.y + v[1] * cs.x;
        v[0] = r0; v[1] = r1;
        #pragma unroll
        for (int ni = 0; ni < 4; ++ni)
          dst[(size_t)t * kD + ni * 16 + n] = f2bf(v[ni] * gain);
      }
  } else {
    // v head kvh = hcol-20: bf16 V^T [b][kv][d][T] + compact fp32 v
    const int kvh = hcol - 20;
    u16* vTb = vT + ((size_t)(bI * kHKV + kvh) * kD) * kT;
    #pragma unroll
    for (int mi = 0; mi < 4; ++mi) {
      const int t0 = (rbase + mi * 16 + quad * 4) & (kT - 1);
      #pragma unroll
      for (int ni = 0; ni < 4; ++ni) {
        const int d = ni * 16 + n;
        *(uint2*)(vTb + (size_t)d * kT + t0) =
            pack4(acc[mi][ni][0], acc[mi][ni][1], acc[mi][ni][2], acc[mi][ni][3]);
        #pragma unroll
        for (int i = 0; i < 4; ++i)
          vcmp[(size_t)(rbase + mi * 16 + quad * 4 + i) * (kHKV * kD) + kvh * kD + d] = acc[mi][ni][i];
      }
    }
  }
}

// -------- output projection GEMM (fp32 C) ------------------------------------
__global__ __launch_bounds__(256) void gemm_out(
    const u16* __restrict__ A, const u16* __restrict__ W,
    float* __restrict__ C)
{
  GEMM128_CORE(A, W, kDim)
  #pragma unroll
  for (int mi = 0; mi < 4; ++mi)
    #pragma unroll
    for (int ni = 0; ni < 4; ++ni)
      #pragma unroll
      for (int i = 0; i < 4; ++i)
        C[(size_t)(m0 + wm + mi * 16 + quad * 4 + i) * kDim + n0 + wn + ni * 16 + n] = acc[mi][ni][i];
}

// ---------------- MFMA causal flash attention, S^T orientation ---------------
// S^T = mfma(K_frag, Q_frag): one softmax row per lane (quad-replicated).
// PV as O^T = mfma(V^T_frag, P_frag). Static max 12 (|q'|<=1.5, |k|=8).
__global__ __launch_bounds__(256) void attn_mfma(
    const u16* __restrict__ qh, const u16* __restrict__ kh,
    const u16* __restrict__ vT, const float* __restrict__ vcmp,
    u16* __restrict__ yo)
{
  __shared__ u16 ks[64][64];     // [key][d],   col ^= (key&7)*8
  __shared__ u16 vs[64][64];     // [d][key],   col ^= (d&7)*8   (V^T)
  __shared__ u16 ps[4][16][64];  // [wave][query][key], col ^= (query&7)*8

  const int tid = threadIdx.x;
  const int lane = tid & 63, wq = tid >> 6;
  const int n = lane & 15, quad = lane >> 4;
  const int p = blockIdx.x;                     // pair 0..15
  const int h = blockIdx.y, b = blockIdx.z;
  const int kv = h >> 2;
  const int tiles[2] = {p, 31 - p};             // tile 0 (short), tile 1 (long)
  const u16* kbase = kh + ((size_t)(b * kHKV + kv) * kT) * kD;
  const u16* vbase = vT + ((size_t)(b * kHKV + kv) * kD) * kT;

  short8 qa[2][2];                // Q B-frags (col=query n, k=d contiguous)
  {
    const u16* qb = qh + ((size_t)(b * kH + h) * kT) * kD;
    #pragma unroll
    for (int u = 0; u < 2; ++u) {
      const size_t row = (size_t)(tiles[u] * 64 + wq * 16 + n) * kD;
      qa[u][0] = *(const short8*)(qb + row + quad * 8);
      qa[u][1] = *(const short8*)(qb + row + 32 + quad * 8);
    }
  }

  const int sr = tid >> 3;            // 0..31 (+32 second chunk)
  const int sc = (tid & 7) * 8;
  const int scs = sc ^ ((sr & 7) * 8);

  float l_r[2] = {0.0f, 0.0f};
  float4v acc[2][4];                  // O^T: [u][d-block g][i]: d=g*16+quad*4+i, query=n
  #pragma unroll
  for (int u = 0; u < 2; ++u)
    #pragma unroll
    for (int g = 0; g < 4; ++g) { acc[u][g][0]=0.f; acc[u][g][1]=0.f; acc[u][g][2]=0.f; acc[u][g][3]=0.f; }

  short8 kr0, kr1, vr0, vr1;
  auto loadKV = [&](int kt) {
    kr0 = *(const short8*)(kbase + (size_t)(kt * 64 + sr) * kD + sc);
    kr1 = *(const short8*)(kbase + (size_t)(kt * 64 + sr + 32) * kD + sc);
    vr0 = *(const short8*)(vbase + (size_t)sr * kT + kt * 64 + sc);
    vr1 = *(const short8*)(vbase + (size_t)(sr + 32) * kT + kt * 64 + sc);
  };

  auto process = [&](int u, int kt) {
    float4v s[4];
    #pragma unroll
    for (int g = 0; g < 4; ++g) { s[g][0]=0.f; s[g][1]=0.f; s[g][2]=0.f; s[g][3]=0.f; }
    // S^T[key][query]: A = K rows, B = Q
    #pragma unroll
    for (int g = 0; g < 4; ++g) {
      const short8 kb0 = *(const short8*)&ks[g * 16 + n][(quad * 8) ^ ((n & 7) * 8)];
      s[g] = __builtin_amdgcn_mfma_f32_16x16x32_bf16(kb0, qa[u][0], s[g], 0, 0, 0);
      const short8 kb1 = *(const short8*)&ks[g * 16 + n][(32 + quad * 8) ^ ((n & 7) * 8)];
      s[g] = __builtin_amdgcn_mfma_f32_16x16x32_bf16(kb1, qa[u][1], s[g], 0, 0, 0);
    }
    if (kt == tiles[u]) {   // diagonal: mask key j > query m (local coords)
      const int mloc = wq * 16 + n;
      #pragma unroll
      for (int g = 0; g < 4; ++g)
        #pragma unroll
        for (int i = 0; i < 4; ++i)
          if (g * 16 + quad * 4 + i > mloc) s[g][i] = -__builtin_inff();
    }
    // softmax: this lane owns ONE query row (16 of its 64 keys)
    float pf[4][4]; float rs = 0.0f;
    #pragma unroll
    for (int g = 0; g < 4; ++g)
      #pragma unroll
      for (int i = 0; i < 4; ++i) { pf[g][i] = __expf(s[g][i] - 12.0f); rs += pf[g][i]; }
    rs += __shfl_xor(rs, 16);
    rs += __shfl_xor(rs, 32);
    l_r[u] += rs;
    #pragma unroll
    for (int g = 0; g < 4; ++g)
      *(uint2*)&ps[wq][n][(g * 16 + quad * 4) ^ ((n & 7) * 8)] =
          pack4(pf[g][0], pf[g][1], pf[g][2], pf[g][3]);   // b64
    // P back as B-frag (row n = query, k = key contiguous); same wave, no barrier
    const short8 pb0 = *(const short8*)&ps[wq][n][(quad * 8) ^ ((n & 7) * 8)];
    const short8 pb1 = *(const short8*)&ps[wq][n][(32 + quad * 8) ^ ((n & 7) * 8)];
    // O^T += V^T * P
    #pragma unroll
    for (int g = 0; g < 4; ++g) {
      const short8 vb0 = *(const short8*)&vs[g * 16 + n][(quad * 8) ^ ((n & 7) * 8)];
      acc[u][g] = __builtin_amdgcn_mfma_f32_16x16x32_bf16(vb0, pb0, acc[u][g], 0, 0, 0);
      const short8 vb1 = *(const short8*)&vs[g * 16 + n][(32 + quad * 8) ^ ((n & 7) * 8)];
      acc[u][g] = __builtin_amdgcn_mfma_f32_16x16x32_bf16(vb1, pb1, acc[u][g], 0, 0, 0);
    }
  };

  const int kmax = tiles[1];
  loadKV(0);
  for (int kt = 0; kt <= kmax; ++kt) {
    __syncthreads();
    *(short8*)&ks[sr][scs]      = kr0;
    *(short8*)&ks[sr + 32][scs] = kr1;
    *(short8*)&vs[sr][scs]      = vr0;
    *(short8*)&vs[sr + 32][scs] = vr1;
    __syncthreads();
    if (kt < kmax) loadKV(kt + 1);
    process(1, kt);                 // long tile, always active
    if (kt <= tiles[0]) process(0, kt);
  }

  // epilogue: y = O/l; remove projection onto normalized v (fp32 from vcmp)
  #pragma unroll
  for (int u = 0; u < 2; ++u) {
    const int tok = b * kT + tiles[u] * 64 + wq * 16 + n;
    const float invl = 1.0f / l_r[u];
    float4 vv[4]; float nn = 0.0f, syr = 0.0f;
    #pragma unroll
    for (int g = 0; g < 4; ++g) {
      vv[g] = *(const float4*)(vcmp + (size_t)tok * (kHKV * kD) + kv * kD + g * 16 + quad * 4);
      nn  += vv[g].x * vv[g].x + vv[g].y * vv[g].y + vv[g].z * vv[g].z + vv[g].w * vv[g].w;
      syr += acc[u][g][0] * vv[g].x + acc[u][g][1] * vv[g].y + acc[u][g][2] * vv[g].z + acc[u][g][3] * vv[g].w;
    }
    nn  += __shfl_xor(nn, 16);  nn  += __shfl_xor(nn, 32);
    syr += __shfl_xor(syr, 16); syr += __shfl_xor(syr, 32);
    const float inv = 1.0f / fmaxf(sqrtf(nn), 1e-12f);
    const float coef = syr * invl * inv * inv;
    #pragma unroll
    for (int g = 0; g < 4; ++g)
      *(uint2*)(yo + (size_t)tok * kDim + h * kD + g * 16 + quad * 4) =
          pack4(acc[u][g][0] * invl - coef * vv[g].x,
                acc[u][g][1] * invl - coef * vv[g].y,
                acc[u][g][2] * invl - coef * vv[g].z,
                acc[u][g][3] * invl - coef * vv[g].w);
  }
}

// ------------------------------- launch --------------------------------------
extern "C" void kernel_launch(void* const* d_in, const int* in_sizes, int n_in,
                              void* d_out, int out_size, void* d_ws, size_t ws_size,
                              hipStream_t stream) {
  (void)in_sizes; (void)n_in; (void)out_size; (void)ws_size;
  const float* x      = (const float*)d_in[0];
  const float* w_q    = (const float*)d_in[1];
  const float* w_k    = (const float*)d_in[2];
  const float* w_v    = (const float*)d_in[3];
  const float* w_proj = (const float*)d_in[4];
  const float* q_gain = (const float*)d_in[5];

  char* wsb = (char*)d_ws;
  u16* wqkv = (u16*)wsb;  wsb += (size_t)1536 * 1024 * 2;   // fused QKV weights
  u16* wpq  = (u16*)wsb;  wsb += (size_t)1024 * 1024 * 2;
  u16* xb   = (u16*)wsb;  wsb += (size_t)kTok * kDim * 2;
  u16* qh   = (u16*)wsb;  wsb += (size_t)kTok * kDim * 2;
  u16* khb  = (u16*)wsb;  wsb += (size_t)kTok * kHKV * kD * 2;
  u16* vTb  = (u16*)wsb;  wsb += (size_t)kTok * kHKV * kD * 2;
  u16* yo   = (u16*)wsb;  wsb += (size_t)kTok * kDim * 2;
  float* vcmp = (float*)wsb; wsb += (size_t)kTok * kHKV * kD * 4;
  float2* ropetab = (float2*)wsb; wsb += (size_t)kT * 16 * sizeof(float2);

  // 1) fused prep: rope table + x->bf16 + all weight fake-quant
  prep_kernel<<<4736, 256, 0, stream>>>(x, w_q, w_k, w_v, w_proj,
                                        xb, wqkv, wpq, ropetab);

  // 2) QKV GEMM (128x128 tile) + fused RMSNorm/RoPE/gain epilogue
  gemm_qkv<<<dim3(12, 32), 256, 0, stream>>>(xb, wqkv, ropetab, q_gain,
                                             qh, khb, vTb, vcmp);

  // 3) paired MFMA flash attention + projection removal -> yo (bf16)
  attn_mfma<<<dim3(16, kH, 2), 256, 0, stream>>>(qh, khb, vTb, vcmp, yo);

  // 4) output projection (fp32 out, 128x128 tile)
  gemm_out<<<dim3(8, 32), 256, 0, stream>>>(yo, wpq, (float*)d_out);
}

// Round 10
// 167.810 us; speedup vs baseline: 1.0159x; 1.0159x over previous
//
#include <hip/hip_runtime.h>
#include <hip/hip_bf16.h>
#include <math.h>

typedef unsigned short u16;
typedef __attribute__((ext_vector_type(8))) short short8;
typedef __attribute__((ext_vector_type(4))) float float4v;
typedef __attribute__((ext_vector_type(4))) u16 ushort4v;

namespace {
constexpr int kT    = 2048;
constexpr int kDim  = 1024;
constexpr int kH    = 16;
constexpr int kHKV  = 4;
constexpr int kD    = 64;
constexpr int kTok  = 4096;   // B*T
}

__device__ __forceinline__ u16 f2bf(float f) {
  unsigned int u = __builtin_bit_cast(unsigned int, f);
  u = (u + 0x7FFFu + ((u >> 16) & 1u)) >> 16;   // RNE
  return (u16)u;
}
__device__ __forceinline__ unsigned pk2(float a, float b) {
  __hip_bfloat162 h = __float22bfloat162_rn(make_float2(a, b));  // v_cvt_pk_bf16_f32
  unsigned u; __builtin_memcpy(&u, &h, 4);
  return u;
}
__device__ __forceinline__ uint2 pack4(float a, float b, float c, float d) {
  return make_uint2(pk2(a, b), pk2(c, d));
}

// async global->LDS DMA, 16B per lane; LDS dest = wave-uniform base + lane*16
__device__ __forceinline__ void gl_lds16(const u16* g, u16* l) {
  __builtin_amdgcn_global_load_lds(
      (const __attribute__((address_space(1))) void*)g,
      (__attribute__((address_space(3))) void*)l, 16, 0, 0);
}

// ---------------- fused prep: rope table + x->bf16 + 4x fake-quant -----------
// blocks [0,128): rope table; [128,2176): cvt x; [2176,4736): quant rows.
__global__ __launch_bounds__(256) void prep_kernel(
    const float* __restrict__ x,
    const float* __restrict__ w_q, const float* __restrict__ w_k,
    const float* __restrict__ w_v, const float* __restrict__ w_proj,
    u16* __restrict__ xb, u16* __restrict__ wqkv, u16* __restrict__ wpq,
    float2* __restrict__ ropetab)
{
  __shared__ float red[4];
  const int bid = blockIdx.x, tid = threadIdx.x;

  if (bid < 128) {                       // rope table (bitwise-same transcendentals)
    const int idx = bid * 256 + tid;     // 0..32767
    const int t = idx >> 4, i = idx & 15;
    const float fr = (float)t * powf(10000.0f, -(float)i * (1.0f / 16.0f));
    ropetab[idx] = make_float2(cosf(fr), sinf(fr));
    return;
  }
  if (bid < 2176) {                      // x -> bf16, 8 elems/thread
    const size_t i = ((size_t)(bid - 128) * 256 + tid) * 8;
    const float4 a = *(const float4*)(x + i);
    const float4 b = *(const float4*)(x + i + 4);
    short8 r;
    r[0] = (short)f2bf(a.x); r[1] = (short)f2bf(a.y);
    r[2] = (short)f2bf(a.z); r[3] = (short)f2bf(a.w);
    r[4] = (short)f2bf(b.x); r[5] = (short)f2bf(b.y);
    r[6] = (short)f2bf(b.z); r[7] = (short)f2bf(b.w);
    *(short8*)(xb + i) = r;
    return;
  }
  // fake-quant: one block per weight row (1024 cols, 4/thread, register-held)
  const int rid = bid - 2176;            // 0..2559
  const float* src; u16* dst; float halfv;
  if (rid < 1024)      { src = w_q    + (size_t)rid * 1024;          dst = wqkv + (size_t)rid * 1024;          halfv = 32.0f; }
  else if (rid < 1280) { src = w_k    + (size_t)(rid - 1024) * 1024; dst = wqkv + (size_t)rid * 1024;          halfv = 32.0f; }
  else if (rid < 1536) { src = w_v    + (size_t)(rid - 1280) * 1024; dst = wqkv + (size_t)rid * 1024;          halfv = 16.0f; }
  else                 { src = w_proj + (size_t)(rid - 1536) * 1024; dst = wpq  + (size_t)(rid - 1536) * 1024; halfv = 16.0f; }

  const float4 v4 = *(const float4*)(src + tid * 4);
  float mx = fmaxf(fmaxf(fabsf(v4.x), fabsf(v4.y)), fmaxf(fabsf(v4.z), fabsf(v4.w)));
  #pragma unroll
  for (int m = 1; m < 64; m <<= 1) mx = fmaxf(mx, __shfl_xor(mx, m));
  if ((tid & 63) == 0) red[tid >> 6] = mx;
  __syncthreads();
  mx = fmaxf(fmaxf(red[0], red[1]), fmaxf(red[2], red[3]));
  const float wmax = fmaxf(mx, 1e-5f);
  const float inv_half = 1.0f / halfv;
  const float vals[4] = {v4.x, v4.y, v4.z, v4.w};
  ushort4v o;
  #pragma unroll
  for (int j = 0; j < 4; ++j) {
    float r = rintf(vals[j] / wmax * halfv);
    r = fminf(fmaxf(r, -halfv), halfv - 1.0f);
    o[j] = f2bf(r * inv_half * wmax);
  }
  *(ushort4v*)(dst + tid * 4) = o;
}

// ======== 128Mx64N bf16 MFMA GEMM core, global_load_lds staging (m97) ========
// 4 waves, each 32Mx64N (mi in {0,1}, ni 0..3): 8 MFMA / 6 ds_read_b128 per
// BK=32 step. Unswizzled [row][32] LDS (DMA needs lane-contiguous layout).
// acc[mi][ni][i]: row = m0 + wv*32 + mi*16 + quad*4 + i, col = ni*16 + n.
#define GEMM_GL_CORE(A_, W_, K_, NROW0_)                                       \
  __shared__ u16 As[128][32];                                                  \
  __shared__ u16 Bs[64][32];                                                   \
  const int tid = threadIdx.x;                                                 \
  const int lane = tid & 63, wv = tid >> 6;                                    \
  const int n = lane & 15, quad = lane >> 4;                                   \
  const int wm = wv * 32;                                                      \
  const int m0 = blockIdx.y * 128;                                             \
  const int lr = lane >> 2, lc = (lane & 3) * 8;                               \
  const u16* gA0 = A_ + (size_t)(m0 + wv * 16 + lr) * K_ + lc;                 \
  const u16* gA1 = gA0 + (size_t)64 * K_;                                      \
  const u16* gB  = W_ + (size_t)(NROW0_ + wv * 16 + lr) * K_ + lc;             \
  u16* lA0 = &As[wv * 16][0];                                                  \
  u16* lA1 = &As[64 + wv * 16][0];                                             \
  u16* lB  = &Bs[wv * 16][0];                                                  \
  float4v acc[2][4];                                                           \
  _Pragma("unroll")                                                            \
  for (int mi = 0; mi < 2; ++mi)                                               \
    _Pragma("unroll")                                                          \
    for (int ni = 0; ni < 4; ++ni) {                                           \
      acc[mi][ni][0]=0.f; acc[mi][ni][1]=0.f;                                  \
      acc[mi][ni][2]=0.f; acc[mi][ni][3]=0.f; }                                \
  for (int k0 = 0; k0 < K_; k0 += 32) {                                        \
    __syncthreads();                                                           \
    gl_lds16(gA0 + k0, lA0);                                                   \
    gl_lds16(gA1 + k0, lA1);                                                   \
    gl_lds16(gB  + k0, lB);                                                    \
    __syncthreads();            /* compiler drains vmcnt before barrier */     \
    short8 af[2], bfr[4];                                                      \
    _Pragma("unroll")                                                          \
    for (int mi = 0; mi < 2; ++mi)                                             \
      af[mi] = *(const short8*)&As[wm + mi * 16 + n][quad * 8];                \
    _Pragma("unroll")                                                          \
    for (int ni = 0; ni < 4; ++ni)                                             \
      bfr[ni] = *(const short8*)&Bs[ni * 16 + n][quad * 8];                    \
    _Pragma("unroll")                                                          \
    for (int mi = 0; mi < 2; ++mi)                                             \
      _Pragma("unroll")                                                        \
      for (int ni = 0; ni < 4; ++ni)                                           \
        acc[mi][ni] = __builtin_amdgcn_mfma_f32_16x16x32_bf16(af[mi], bfr[ni], acc[mi][ni], 0, 0, 0); \
  }

// -------- QKV GEMM with fused RMSNorm+RoPE+gain epilogue ---------------------
// Block = one 64-col head panel: blockIdx.x = 0..15 q, 16..19 k, 20..23 v.
__global__ __launch_bounds__(256) void gemm_qkv(
    const u16* __restrict__ A, const u16* __restrict__ W,
    const float2* __restrict__ ropetab, const float* __restrict__ q_gain,
    u16* __restrict__ qh, u16* __restrict__ kh,
    u16* __restrict__ vT, float* __restrict__ vcmp)
{
  GEMM_GL_CORE(A, W, kDim, (int)(blockIdx.x * 64))

  const int p = blockIdx.x;
  const int rbase = m0 + wm;                 // + mi*16 + quad*4 + i = token row
  const int bI = rbase >> 11;                // batch (128-row tiles never straddle)

  if (p < 20) {
    // q (head p) or k (head p-16): RMSNorm over 64 dims + RoPE + gain
    const float gain = (p < 16) ? q_gain[p] * 0.125f : 1.0f;
    u16* dst = (p < 16) ? qh + ((size_t)(bI * kH + p) * kT) * kD
                        : kh + ((size_t)(bI * kHKV + (p - 16)) * kT) * kD;
    #pragma unroll
    for (int mi = 0; mi < 2; ++mi)
      #pragma unroll
      for (int i = 0; i < 4; ++i) {
        const int row = rbase + mi * 16 + quad * 4 + i;
        const int t = row & (kT - 1);
        float v[4];
        #pragma unroll
        for (int ni = 0; ni < 4; ++ni) v[ni] = acc[mi][ni][i];
        float ss = v[0]*v[0] + v[1]*v[1] + v[2]*v[2] + v[3]*v[3];
        #pragma unroll
        for (int m = 1; m < 16; m <<= 1) ss += __shfl_xor(ss, m);
        const float rr = 1.0f / sqrtf(ss * (1.0f / 64.0f) + 1.1920929e-7f);
        #pragma unroll
        for (int ni = 0; ni < 4; ++ni) v[ni] *= rr;
        const float2 cs = ropetab[t * 16 + n];
        const float r0 =  v[0] * cs.x + v[1] * cs.y;
        const float r1 = -v[0] * cs.y + v[1] * cs.x;
        v[0] = r0; v[1] = r1;
        #pragma unroll
        for (int ni = 0; ni < 4; ++ni)
          dst[(size_t)t * kD + ni * 16 + n] = f2bf(v[ni] * gain);
      }
  } else {
    // v head kvh = p-20: bf16 V^T [b][kv][d][T] + compact fp32 v
    const int kvh = p - 20;
    u16* vTb = vT + ((size_t)(bI * kHKV + kvh) * kD) * kT;
    #pragma unroll
    for (int mi = 0; mi < 2; ++mi) {
      const int t0 = (rbase + mi * 16 + quad * 4) & (kT - 1);
      #pragma unroll
      for (int ni = 0; ni < 4; ++ni) {
        const int d = ni * 16 + n;
        *(uint2*)(vTb + (size_t)d * kT + t0) =
            pack4(acc[mi][ni][0], acc[mi][ni][1], acc[mi][ni][2], acc[mi][ni][3]);
        #pragma unroll
        for (int i = 0; i < 4; ++i)
          vcmp[(size_t)(rbase + mi * 16 + quad * 4 + i) * (kHKV * kD) + kvh * kD + d] = acc[mi][ni][i];
      }
    }
  }
}

// -------- output projection GEMM (fp32 C) ------------------------------------
__global__ __launch_bounds__(256) void gemm_out(
    const u16* __restrict__ A, const u16* __restrict__ W,
    float* __restrict__ C)
{
  GEMM_GL_CORE(A, W, kDim, (int)(blockIdx.x * 64))
  const int n0 = blockIdx.x * 64;
  #pragma unroll
  for (int mi = 0; mi < 2; ++mi)
    #pragma unroll
    for (int ni = 0; ni < 4; ++ni)
      #pragma unroll
      for (int i = 0; i < 4; ++i)
        C[(size_t)(m0 + wm + mi * 16 + quad * 4 + i) * kDim + n0 + ni * 16 + n] = acc[mi][ni][i];
}

// ---------------- MFMA causal flash attention, S^T orientation ---------------
// S^T = mfma(K_frag, Q_frag): one softmax row per lane (quad-replicated).
// PV as O^T = mfma(V^T_frag, P_frag). Static max 12 (|q'|<=1.5, |k|=8).
__global__ __launch_bounds__(256) void attn_mfma(
    const u16* __restrict__ qh, const u16* __restrict__ kh,
    const u16* __restrict__ vT, const float* __restrict__ vcmp,
    u16* __restrict__ yo)
{
  __shared__ u16 ks[64][64];     // [key][d],   col ^= (key&7)*8
  __shared__ u16 vs[64][64];     // [d][key],   col ^= (d&7)*8   (V^T)
  __shared__ u16 ps[4][16][64];  // [wave][query][key], col ^= (query&7)*8

  const int tid = threadIdx.x;
  const int lane = tid & 63, wq = tid >> 6;
  const int n = lane & 15, quad = lane >> 4;
  const int p = blockIdx.x;                     // pair 0..15
  const int h = blockIdx.y, b = blockIdx.z;
  const int kv = h >> 2;
  const int tiles[2] = {p, 31 - p};             // tile 0 (short), tile 1 (long)
  const u16* kbase = kh + ((size_t)(b * kHKV + kv) * kT) * kD;
  const u16* vbase = vT + ((size_t)(b * kHKV + kv) * kD) * kT;

  short8 qa[2][2];                // Q B-frags (col=query n, k=d contiguous)
  {
    const u16* qb = qh + ((size_t)(b * kH + h) * kT) * kD;
    #pragma unroll
    for (int u = 0; u < 2; ++u) {
      const size_t row = (size_t)(tiles[u] * 64 + wq * 16 + n) * kD;
      qa[u][0] = *(const short8*)(qb + row + quad * 8);
      qa[u][1] = *(const short8*)(qb + row + 32 + quad * 8);
    }
  }

  const int sr = tid >> 3;            // 0..31 (+32 second chunk)
  const int sc = (tid & 7) * 8;
  const int scs = sc ^ ((sr & 7) * 8);

  float l_r[2] = {0.0f, 0.0f};
  float4v acc[2][4];                  // O^T: [u][d-block g][i]: d=g*16+quad*4+i, query=n
  #pragma unroll
  for (int u = 0; u < 2; ++u)
    #pragma unroll
    for (int g = 0; g < 4; ++g) { acc[u][g][0]=0.f; acc[u][g][1]=0.f; acc[u][g][2]=0.f; acc[u][g][3]=0.f; }

  short8 kr0, kr1, vr0, vr1;
  auto loadKV = [&](int kt) {
    kr0 = *(const short8*)(kbase + (size_t)(kt * 64 + sr) * kD + sc);
    kr1 = *(const short8*)(kbase + (size_t)(kt * 64 + sr + 32) * kD + sc);
    vr0 = *(const short8*)(vbase + (size_t)sr * kT + kt * 64 + sc);
    vr1 = *(const short8*)(vbase + (size_t)(sr + 32) * kT + kt * 64 + sc);
  };

  auto process = [&](int u, int kt) {
    float4v s[4];
    #pragma unroll
    for (int g = 0; g < 4; ++g) { s[g][0]=0.f; s[g][1]=0.f; s[g][2]=0.f; s[g][3]=0.f; }
    // S^T[key][query]: A = K rows, B = Q
    #pragma unroll
    for (int g = 0; g < 4; ++g) {
      const short8 kb0 = *(const short8*)&ks[g * 16 + n][(quad * 8) ^ ((n & 7) * 8)];
      s[g] = __builtin_amdgcn_mfma_f32_16x16x32_bf16(kb0, qa[u][0], s[g], 0, 0, 0);
      const short8 kb1 = *(const short8*)&ks[g * 16 + n][(32 + quad * 8) ^ ((n & 7) * 8)];
      s[g] = __builtin_amdgcn_mfma_f32_16x16x32_bf16(kb1, qa[u][1], s[g], 0, 0, 0);
    }
    if (kt == tiles[u]) {   // diagonal: mask key j > query m (local coords)
      const int mloc = wq * 16 + n;
      #pragma unroll
      for (int g = 0; g < 4; ++g)
        #pragma unroll
        for (int i = 0; i < 4; ++i)
          if (g * 16 + quad * 4 + i > mloc) s[g][i] = -__builtin_inff();
    }
    // softmax: this lane owns ONE query row (16 of its 64 keys)
    float pf[4][4]; float rs = 0.0f;
    #pragma unroll
    for (int g = 0; g < 4; ++g)
      #pragma unroll
      for (int i = 0; i < 4; ++i) { pf[g][i] = __expf(s[g][i] - 12.0f); rs += pf[g][i]; }
    rs += __shfl_xor(rs, 16);
    rs += __shfl_xor(rs, 32);
    l_r[u] += rs;
    #pragma unroll
    for (int g = 0; g < 4; ++g)
      *(uint2*)&ps[wq][n][(g * 16 + quad * 4) ^ ((n & 7) * 8)] =
          pack4(pf[g][0], pf[g][1], pf[g][2], pf[g][3]);   // b64
    // P back as B-frag (row n = query, k = key contiguous); same wave, no barrier
    const short8 pb0 = *(const short8*)&ps[wq][n][(quad * 8) ^ ((n & 7) * 8)];
    const short8 pb1 = *(const short8*)&ps[wq][n][(32 + quad * 8) ^ ((n & 7) * 8)];
    // O^T += V^T * P
    #pragma unroll
    for (int g = 0; g < 4; ++g) {
      const short8 vb0 = *(const short8*)&vs[g * 16 + n][(quad * 8) ^ ((n & 7) * 8)];
      acc[u][g] = __builtin_amdgcn_mfma_f32_16x16x32_bf16(vb0, pb0, acc[u][g], 0, 0, 0);
      const short8 vb1 = *(const short8*)&vs[g * 16 + n][(32 + quad * 8) ^ ((n & 7) * 8)];
      acc[u][g] = __builtin_amdgcn_mfma_f32_16x16x32_bf16(vb1, pb1, acc[u][g], 0, 0, 0);
    }
  };

  const int kmax = tiles[1];
  loadKV(0);
  for (int kt = 0; kt <= kmax; ++kt) {
    __syncthreads();
    *(short8*)&ks[sr][scs]      = kr0;
    *(short8*)&ks[sr + 32][scs] = kr1;
    *(short8*)&vs[sr][scs]      = vr0;
    *(short8*)&vs[sr + 32][scs] = vr1;
    __syncthreads();
    if (kt < kmax) loadKV(kt + 1);
    process(1, kt);                 // long tile, always active
    if (kt <= tiles[0]) process(0, kt);
  }

  // epilogue: y = O/l; remove projection onto normalized v (fp32 from vcmp)
  #pragma unroll
  for (int u = 0; u < 2; ++u) {
    const int tok = b * kT + tiles[u] * 64 + wq * 16 + n;
    const float invl = 1.0f / l_r[u];
    float4 vv[4]; float nn = 0.0f, syr = 0.0f;
    #pragma unroll
    for (int g = 0; g < 4; ++g) {
      vv[g] = *(const float4*)(vcmp + (size_t)tok * (kHKV * kD) + kv * kD + g * 16 + quad * 4);
      nn  += vv[g].x * vv[g].x + vv[g].y * vv[g].y + vv[g].z * vv[g].z + vv[g].w * vv[g].w;
      syr += acc[u][g][0] * vv[g].x + acc[u][g][1] * vv[g].y + acc[u][g][2] * vv[g].z + acc[u][g][3] * vv[g].w;
    }
    nn  += __shfl_xor(nn, 16);  nn  += __shfl_xor(nn, 32);
    syr += __shfl_xor(syr, 16); syr += __shfl_xor(syr, 32);
    const float inv = 1.0f / fmaxf(sqrtf(nn), 1e-12f);
    const float coef = syr * invl * inv * inv;
    #pragma unroll
    for (int g = 0; g < 4; ++g)
      *(uint2*)(yo + (size_t)tok * kDim + h * kD + g * 16 + quad * 4) =
          pack4(acc[u][g][0] * invl - coef * vv[g].x,
                acc[u][g][1] * invl - coef * vv[g].y,
                acc[u][g][2] * invl - coef * vv[g].z,
                acc[u][g][3] * invl - coef * vv[g].w);
  }
}

// ------------------------------- launch --------------------------------------
extern "C" void kernel_launch(void* const* d_in, const int* in_sizes, int n_in,
                              void* d_out, int out_size, void* d_ws, size_t ws_size,
                              hipStream_t stream) {
  (void)in_sizes; (void)n_in; (void)out_size; (void)ws_size;
  const float* x      = (const float*)d_in[0];
  const float* w_q    = (const float*)d_in[1];
  const float* w_k    = (const float*)d_in[2];
  const float* w_v    = (const float*)d_in[3];
  const float* w_proj = (const float*)d_in[4];
  const float* q_gain = (const float*)d_in[5];

  char* wsb = (char*)d_ws;
  u16* wqkv = (u16*)wsb;  wsb += (size_t)1536 * 1024 * 2;   // fused QKV weights
  u16* wpq  = (u16*)wsb;  wsb += (size_t)1024 * 1024 * 2;
  u16* xb   = (u16*)wsb;  wsb += (size_t)kTok * kDim * 2;
  u16* qh   = (u16*)wsb;  wsb += (size_t)kTok * kDim * 2;
  u16* khb  = (u16*)wsb;  wsb += (size_t)kTok * kHKV * kD * 2;
  u16* vTb  = (u16*)wsb;  wsb += (size_t)kTok * kHKV * kD * 2;
  u16* yo   = (u16*)wsb;  wsb += (size_t)kTok * kDim * 2;
  float* vcmp = (float*)wsb; wsb += (size_t)kTok * kHKV * kD * 4;
  float2* ropetab = (float2*)wsb; wsb += (size_t)kT * 16 * sizeof(float2);

  // 1) fused prep: rope table + x->bf16 + all weight fake-quant
  prep_kernel<<<4736, 256, 0, stream>>>(x, w_q, w_k, w_v, w_proj,
                                        xb, wqkv, wpq, ropetab);

  // 2) QKV GEMM (128x64, global_load_lds) + fused RMSNorm/RoPE/gain epilogue
  gemm_qkv<<<dim3(24, 32), 256, 0, stream>>>(xb, wqkv, ropetab, q_gain,
                                             qh, khb, vTb, vcmp);

  // 3) paired MFMA flash attention + projection removal -> yo (bf16)
  attn_mfma<<<dim3(16, kH, 2), 256, 0, stream>>>(qh, khb, vTb, vcmp, yo);

  // 4) output projection (fp32 out, 128x64, global_load_lds)
  gemm_out<<<dim3(16, 32), 256, 0, stream>>>(yo, wpq, (float*)d_out);
}

// Round 11
// 167.696 us; speedup vs baseline: 1.0166x; 1.0007x over previous
//
#include <hip/hip_runtime.h>
#include <hip/hip_bf16.h>
#include <math.h>

typedef unsigned short u16;
typedef __attribute__((ext_vector_type(8))) short short8;
typedef __attribute__((ext_vector_type(4))) float float4v;
typedef __attribute__((ext_vector_type(4))) u16 ushort4v;

namespace {
constexpr int kT    = 2048;
constexpr int kDim  = 1024;
constexpr int kH    = 16;
constexpr int kHKV  = 4;
constexpr int kD    = 64;
constexpr int kTok  = 4096;   // B*T
}

__device__ __forceinline__ u16 f2bf(float f) {
  unsigned int u = __builtin_bit_cast(unsigned int, f);
  u = (u + 0x7FFFu + ((u >> 16) & 1u)) >> 16;   // RNE
  return (u16)u;
}
__device__ __forceinline__ unsigned pk2(float a, float b) {
  __hip_bfloat162 h = __float22bfloat162_rn(make_float2(a, b));  // v_cvt_pk_bf16_f32
  unsigned u; __builtin_memcpy(&u, &h, 4);
  return u;
}
__device__ __forceinline__ uint2 pack4(float a, float b, float c, float d) {
  return make_uint2(pk2(a, b), pk2(c, d));
}

// async global->LDS DMA, 16B per lane; LDS dest = wave-uniform base + lane*16
__device__ __forceinline__ void gl_lds16(const u16* g, u16* l) {
  __builtin_amdgcn_global_load_lds(
      (const __attribute__((address_space(1))) void*)g,
      (__attribute__((address_space(3))) void*)l, 16, 0, 0);
}

// ---------------- fused prep: rope table + x->bf16 + 4x fake-quant -----------
// blocks [0,128): rope table; [128,2176): cvt x; [2176,4736): quant rows.
__global__ __launch_bounds__(256) void prep_kernel(
    const float* __restrict__ x,
    const float* __restrict__ w_q, const float* __restrict__ w_k,
    const float* __restrict__ w_v, const float* __restrict__ w_proj,
    u16* __restrict__ xb, u16* __restrict__ wqkv, u16* __restrict__ wpq,
    float2* __restrict__ ropetab)
{
  __shared__ float red[4];
  const int bid = blockIdx.x, tid = threadIdx.x;

  if (bid < 128) {                       // rope table (bitwise-same transcendentals)
    const int idx = bid * 256 + tid;     // 0..32767
    const int t = idx >> 4, i = idx & 15;
    const float fr = (float)t * powf(10000.0f, -(float)i * (1.0f / 16.0f));
    ropetab[idx] = make_float2(cosf(fr), sinf(fr));
    return;
  }
  if (bid < 2176) {                      // x -> bf16, 8 elems/thread
    const size_t i = ((size_t)(bid - 128) * 256 + tid) * 8;
    const float4 a = *(const float4*)(x + i);
    const float4 b = *(const float4*)(x + i + 4);
    short8 r;
    r[0] = (short)f2bf(a.x); r[1] = (short)f2bf(a.y);
    r[2] = (short)f2bf(a.z); r[3] = (short)f2bf(a.w);
    r[4] = (short)f2bf(b.x); r[5] = (short)f2bf(b.y);
    r[6] = (short)f2bf(b.z); r[7] = (short)f2bf(b.w);
    *(short8*)(xb + i) = r;
    return;
  }
  // fake-quant: one block per weight row (1024 cols, 4/thread, register-held)
  const int rid = bid - 2176;            // 0..2559
  const float* src; u16* dst; float halfv;
  if (rid < 1024)      { src = w_q    + (size_t)rid * 1024;          dst = wqkv + (size_t)rid * 1024;          halfv = 32.0f; }
  else if (rid < 1280) { src = w_k    + (size_t)(rid - 1024) * 1024; dst = wqkv + (size_t)rid * 1024;          halfv = 32.0f; }
  else if (rid < 1536) { src = w_v    + (size_t)(rid - 1280) * 1024; dst = wqkv + (size_t)rid * 1024;          halfv = 16.0f; }
  else                 { src = w_proj + (size_t)(rid - 1536) * 1024; dst = wpq  + (size_t)(rid - 1536) * 1024; halfv = 16.0f; }

  const float4 v4 = *(const float4*)(src + tid * 4);
  float mx = fmaxf(fmaxf(fabsf(v4.x), fabsf(v4.y)), fmaxf(fabsf(v4.z), fabsf(v4.w)));
  #pragma unroll
  for (int m = 1; m < 64; m <<= 1) mx = fmaxf(mx, __shfl_xor(mx, m));
  if ((tid & 63) == 0) red[tid >> 6] = mx;
  __syncthreads();
  mx = fmaxf(fmaxf(red[0], red[1]), fmaxf(red[2], red[3]));
  const float wmax = fmaxf(mx, 1e-5f);
  const float inv_half = 1.0f / halfv;
  const float vals[4] = {v4.x, v4.y, v4.z, v4.w};
  ushort4v o;
  #pragma unroll
  for (int j = 0; j < 4; ++j) {
    float r = rintf(vals[j] / wmax * halfv);
    r = fminf(fmaxf(r, -halfv), halfv - 1.0f);
    o[j] = f2bf(r * inv_half * wmax);
  }
  *(ushort4v*)(dst + tid * 4) = o;
}

// ======== 128Mx64N bf16 MFMA GEMM core, BK=64, global_load_lds staging =======
// 16 K-steps (vs 32 at BK=32): half the barrier+vmcnt-drain events.
// Per wave per step: 6 DMA, 12 ds_read_b128, 16 MFMA.
// acc[mi][ni][i]: row = m0 + wv*32 + mi*16 + quad*4 + i, col = ni*16 + n.
#define GEMM_GL_CORE(A_, W_, K_, NROW0_)                                       \
  __shared__ u16 As[128][64];                                                  \
  __shared__ u16 Bs[64][64];                                                   \
  const int tid = threadIdx.x;                                                 \
  const int lane = tid & 63, wv = tid >> 6;                                    \
  const int n = lane & 15, quad = lane >> 4;                                   \
  const int wm = wv * 32;                                                      \
  const int m0 = blockIdx.y * 128;                                             \
  const int lr8 = lane >> 3, lc8 = (lane & 7) * 8;                             \
  const u16* gA = A_ + (size_t)(m0 + wv * 32 + lr8) * K_ + lc8;                \
  const u16* gB = W_ + (size_t)(NROW0_ + wv * 16 + lr8) * K_ + lc8;            \
  float4v acc[2][4];                                                           \
  _Pragma("unroll")                                                            \
  for (int mi = 0; mi < 2; ++mi)                                               \
    _Pragma("unroll")                                                          \
    for (int ni = 0; ni < 4; ++ni) {                                           \
      acc[mi][ni][0]=0.f; acc[mi][ni][1]=0.f;                                  \
      acc[mi][ni][2]=0.f; acc[mi][ni][3]=0.f; }                                \
  for (int k0 = 0; k0 < K_; k0 += 64) {                                        \
    __syncthreads();                                                           \
    _Pragma("unroll")                                                          \
    for (int j = 0; j < 4; ++j)                                                \
      gl_lds16(gA + (size_t)(j * 8) * K_ + k0, &As[wv * 32 + j * 8][0]);       \
    _Pragma("unroll")                                                          \
    for (int j = 0; j < 2; ++j)                                                \
      gl_lds16(gB + (size_t)(j * 8) * K_ + k0, &Bs[wv * 16 + j * 8][0]);       \
    __syncthreads();            /* compiler drains vmcnt before barrier */     \
    _Pragma("unroll")                                                          \
    for (int kk = 0; kk < 2; ++kk) {                                           \
      short8 af[2], bfr[4];                                                    \
      _Pragma("unroll")                                                        \
      for (int mi = 0; mi < 2; ++mi)                                           \
        af[mi] = *(const short8*)&As[wm + mi * 16 + n][kk * 32 + quad * 8];    \
      _Pragma("unroll")                                                        \
      for (int ni = 0; ni < 4; ++ni)                                           \
        bfr[ni] = *(const short8*)&Bs[ni * 16 + n][kk * 32 + quad * 8];        \
      _Pragma("unroll")                                                        \
      for (int mi = 0; mi < 2; ++mi)                                           \
        _Pragma("unroll")                                                      \
        for (int ni = 0; ni < 4; ++ni)                                         \
          acc[mi][ni] = __builtin_amdgcn_mfma_f32_16x16x32_bf16(af[mi], bfr[ni], acc[mi][ni], 0, 0, 0); \
    }                                                                          \
  }

// -------- QKV GEMM with fused RMSNorm+RoPE+gain epilogue ---------------------
// Block = one 64-col head panel: blockIdx.x = 0..15 q, 16..19 k, 20..23 v.
__global__ __launch_bounds__(256) void gemm_qkv(
    const u16* __restrict__ A, const u16* __restrict__ W,
    const float2* __restrict__ ropetab, const float* __restrict__ q_gain,
    u16* __restrict__ qh, u16* __restrict__ kh,
    u16* __restrict__ vT, float* __restrict__ vcmp)
{
  GEMM_GL_CORE(A, W, kDim, (int)(blockIdx.x * 64))

  const int p = blockIdx.x;
  const int rbase = m0 + wm;                 // + mi*16 + quad*4 + i = token row
  const int bI = rbase >> 11;                // batch (128-row tiles never straddle)

  if (p < 20) {
    // q (head p) or k (head p-16): RMSNorm over 64 dims + RoPE + gain
    const float gain = (p < 16) ? q_gain[p] * 0.125f : 1.0f;
    u16* dst = (p < 16) ? qh + ((size_t)(bI * kH + p) * kT) * kD
                        : kh + ((size_t)(bI * kHKV + (p - 16)) * kT) * kD;
    #pragma unroll
    for (int mi = 0; mi < 2; ++mi)
      #pragma unroll
      for (int i = 0; i < 4; ++i) {
        const int row = rbase + mi * 16 + quad * 4 + i;
        const int t = row & (kT - 1);
        float v[4];
        #pragma unroll
        for (int ni = 0; ni < 4; ++ni) v[ni] = acc[mi][ni][i];
        float ss = v[0]*v[0] + v[1]*v[1] + v[2]*v[2] + v[3]*v[3];
        #pragma unroll
        for (int m = 1; m < 16; m <<= 1) ss += __shfl_xor(ss, m);
        const float rr = 1.0f / sqrtf(ss * (1.0f / 64.0f) + 1.1920929e-7f);
        #pragma unroll
        for (int ni = 0; ni < 4; ++ni) v[ni] *= rr;
        const float2 cs = ropetab[t * 16 + n];
        const float r0 =  v[0] * cs.x + v[1] * cs.y;
        const float r1 = -v[0] * cs.y + v[1] * cs.x;
        v[0] = r0; v[1] = r1;
        #pragma unroll
        for (int ni = 0; ni < 4; ++ni)
          dst[(size_t)t * kD + ni * 16 + n] = f2bf(v[ni] * gain);
      }
  } else {
    // v head kvh = p-20: bf16 V^T [b][kv][d][T] + compact fp32 v
    const int kvh = p - 20;
    u16* vTb = vT + ((size_t)(bI * kHKV + kvh) * kD) * kT;
    #pragma unroll
    for (int mi = 0; mi < 2; ++mi) {
      const int t0 = (rbase + mi * 16 + quad * 4) & (kT - 1);
      #pragma unroll
      for (int ni = 0; ni < 4; ++ni) {
        const int d = ni * 16 + n;
        *(uint2*)(vTb + (size_t)d * kT + t0) =
            pack4(acc[mi][ni][0], acc[mi][ni][1], acc[mi][ni][2], acc[mi][ni][3]);
        #pragma unroll
        for (int i = 0; i < 4; ++i)
          vcmp[(size_t)(rbase + mi * 16 + quad * 4 + i) * (kHKV * kD) + kvh * kD + d] = acc[mi][ni][i];
      }
    }
  }
}

// -------- output projection GEMM (fp32 C) ------------------------------------
__global__ __launch_bounds__(256) void gemm_out(
    const u16* __restrict__ A, const u16* __restrict__ W,
    float* __restrict__ C)
{
  GEMM_GL_CORE(A, W, kDim, (int)(blockIdx.x * 64))
  const int n0 = blockIdx.x * 64;
  #pragma unroll
  for (int mi = 0; mi < 2; ++mi)
    #pragma unroll
    for (int ni = 0; ni < 4; ++ni)
      #pragma unroll
      for (int i = 0; i < 4; ++i)
        C[(size_t)(m0 + wm + mi * 16 + quad * 4 + i) * kDim + n0 + ni * 16 + n] = acc[mi][ni][i];
}

// ---------------- MFMA causal flash attention, S^T orientation ---------------
// S^T = mfma(K_frag, Q_frag): one softmax row per lane (quad-replicated).
// PV as O^T = mfma(V^T_frag, P_frag). Static max 12 (|q'|<=1.5, |k|=8).
__global__ __launch_bounds__(256) void attn_mfma(
    const u16* __restrict__ qh, const u16* __restrict__ kh,
    const u16* __restrict__ vT, const float* __restrict__ vcmp,
    u16* __restrict__ yo)
{
  __shared__ u16 ks[64][64];     // [key][d],   col ^= (key&7)*8
  __shared__ u16 vs[64][64];     // [d][key],   col ^= (d&7)*8   (V^T)
  __shared__ u16 ps[4][16][64];  // [wave][query][key], col ^= (query&7)*8

  const int tid = threadIdx.x;
  const int lane = tid & 63, wq = tid >> 6;
  const int n = lane & 15, quad = lane >> 4;
  const int p = blockIdx.x;                     // pair 0..15
  const int h = blockIdx.y, b = blockIdx.z;
  const int kv = h >> 2;
  const int tiles[2] = {p, 31 - p};             // tile 0 (short), tile 1 (long)
  const u16* kbase = kh + ((size_t)(b * kHKV + kv) * kT) * kD;
  const u16* vbase = vT + ((size_t)(b * kHKV + kv) * kD) * kT;

  short8 qa[2][2];                // Q B-frags (col=query n, k=d contiguous)
  {
    const u16* qb = qh + ((size_t)(b * kH + h) * kT) * kD;
    #pragma unroll
    for (int u = 0; u < 2; ++u) {
      const size_t row = (size_t)(tiles[u] * 64 + wq * 16 + n) * kD;
      qa[u][0] = *(const short8*)(qb + row + quad * 8);
      qa[u][1] = *(const short8*)(qb + row + 32 + quad * 8);
    }
  }

  const int sr = tid >> 3;            // 0..31 (+32 second chunk)
  const int sc = (tid & 7) * 8;
  const int scs = sc ^ ((sr & 7) * 8);

  float l_r[2] = {0.0f, 0.0f};
  float4v acc[2][4];                  // O^T: [u][d-block g][i]: d=g*16+quad*4+i, query=n
  #pragma unroll
  for (int u = 0; u < 2; ++u)
    #pragma unroll
    for (int g = 0; g < 4; ++g) { acc[u][g][0]=0.f; acc[u][g][1]=0.f; acc[u][g][2]=0.f; acc[u][g][3]=0.f; }

  short8 kr0, kr1, vr0, vr1;
  auto loadKV = [&](int kt) {
    kr0 = *(const short8*)(kbase + (size_t)(kt * 64 + sr) * kD + sc);
    kr1 = *(const short8*)(kbase + (size_t)(kt * 64 + sr + 32) * kD + sc);
    vr0 = *(const short8*)(vbase + (size_t)sr * kT + kt * 64 + sc);
    vr1 = *(const short8*)(vbase + (size_t)(sr + 32) * kT + kt * 64 + sc);
  };

  auto process = [&](int u, int kt) {
    float4v s[4];
    #pragma unroll
    for (int g = 0; g < 4; ++g) { s[g][0]=0.f; s[g][1]=0.f; s[g][2]=0.f; s[g][3]=0.f; }
    // S^T[key][query]: A = K rows, B = Q
    #pragma unroll
    for (int g = 0; g < 4; ++g) {
      const short8 kb0 = *(const short8*)&ks[g * 16 + n][(quad * 8) ^ ((n & 7) * 8)];
      s[g] = __builtin_amdgcn_mfma_f32_16x16x32_bf16(kb0, qa[u][0], s[g], 0, 0, 0);
      const short8 kb1 = *(const short8*)&ks[g * 16 + n][(32 + quad * 8) ^ ((n & 7) * 8)];
      s[g] = __builtin_amdgcn_mfma_f32_16x16x32_bf16(kb1, qa[u][1], s[g], 0, 0, 0);
    }
    if (kt == tiles[u]) {   // diagonal: mask key j > query m (local coords)
      const int mloc = wq * 16 + n;
      #pragma unroll
      for (int g = 0; g < 4; ++g)
        #pragma unroll
        for (int i = 0; i < 4; ++i)
          if (g * 16 + quad * 4 + i > mloc) s[g][i] = -__builtin_inff();
    }
    // softmax: this lane owns ONE query row (16 of its 64 keys)
    float pf[4][4]; float rs = 0.0f;
    #pragma unroll
    for (int g = 0; g < 4; ++g)
      #pragma unroll
      for (int i = 0; i < 4; ++i) { pf[g][i] = __expf(s[g][i] - 12.0f); rs += pf[g][i]; }
    rs += __shfl_xor(rs, 16);
    rs += __shfl_xor(rs, 32);
    l_r[u] += rs;
    #pragma unroll
    for (int g = 0; g < 4; ++g)
      *(uint2*)&ps[wq][n][(g * 16 + quad * 4) ^ ((n & 7) * 8)] =
          pack4(pf[g][0], pf[g][1], pf[g][2], pf[g][3]);   // b64
    // P back as B-frag (row n = query, k = key contiguous); same wave, no barrier
    const short8 pb0 = *(const short8*)&ps[wq][n][(quad * 8) ^ ((n & 7) * 8)];
    const short8 pb1 = *(const short8*)&ps[wq][n][(32 + quad * 8) ^ ((n & 7) * 8)];
    // O^T += V^T * P
    #pragma unroll
    for (int g = 0; g < 4; ++g) {
      const short8 vb0 = *(const short8*)&vs[g * 16 + n][(quad * 8) ^ ((n & 7) * 8)];
      acc[u][g] = __builtin_amdgcn_mfma_f32_16x16x32_bf16(vb0, pb0, acc[u][g], 0, 0, 0);
      const short8 vb1 = *(const short8*)&vs[g * 16 + n][(32 + quad * 8) ^ ((n & 7) * 8)];
      acc[u][g] = __builtin_amdgcn_mfma_f32_16x16x32_bf16(vb1, pb1, acc[u][g], 0, 0, 0);
    }
  };

  const int kmax = tiles[1];
  loadKV(0);
  for (int kt = 0; kt <= kmax; ++kt) {
    __syncthreads();
    *(short8*)&ks[sr][scs]      = kr0;
    *(short8*)&ks[sr + 32][scs] = kr1;
    *(short8*)&vs[sr][scs]      = vr0;
    *(short8*)&vs[sr + 32][scs] = vr1;
    __syncthreads();
    if (kt < kmax) loadKV(kt + 1);
    process(1, kt);                 // long tile, always active
    if (kt <= tiles[0]) process(0, kt);
  }

  // epilogue: y = O/l; remove projection onto normalized v (fp32 from vcmp)
  #pragma unroll
  for (int u = 0; u < 2; ++u) {
    const int tok = b * kT + tiles[u] * 64 + wq * 16 + n;
    const float invl = 1.0f / l_r[u];
    float4 vv[4]; float nn = 0.0f, syr = 0.0f;
    #pragma unroll
    for (int g = 0; g < 4; ++g) {
      vv[g] = *(const float4*)(vcmp + (size_t)tok * (kHKV * kD) + kv * kD + g * 16 + quad * 4);
      nn  += vv[g].x * vv[g].x + vv[g].y * vv[g].y + vv[g].z * vv[g].z + vv[g].w * vv[g].w;
      syr += acc[u][g][0] * vv[g].x + acc[u][g][1] * vv[g].y + acc[u][g][2] * vv[g].z + acc[u][g][3] * vv[g].w;
    }
    nn  += __shfl_xor(nn, 16);  nn  += __shfl_xor(nn, 32);
    syr += __shfl_xor(syr, 16); syr += __shfl_xor(syr, 32);
    const float inv = 1.0f / fmaxf(sqrtf(nn), 1e-12f);
    const float coef = syr * invl * inv * inv;
    #pragma unroll
    for (int g = 0; g < 4; ++g)
      *(uint2*)(yo + (size_t)tok * kDim + h * kD + g * 16 + quad * 4) =
          pack4(acc[u][g][0] * invl - coef * vv[g].x,
                acc[u][g][1] * invl - coef * vv[g].y,
                acc[u][g][2] * invl - coef * vv[g].z,
                acc[u][g][3] * invl - coef * vv[g].w);
  }
}

// ------------------------------- launch --------------------------------------
extern "C" void kernel_launch(void* const* d_in, const int* in_sizes, int n_in,
                              void* d_out, int out_size, void* d_ws, size_t ws_size,
                              hipStream_t stream) {
  (void)in_sizes; (void)n_in; (void)out_size; (void)ws_size;
  const float* x      = (const float*)d_in[0];
  const float* w_q    = (const float*)d_in[1];
  const float* w_k    = (const float*)d_in[2];
  const float* w_v    = (const float*)d_in[3];
  const float* w_proj = (const float*)d_in[4];
  const float* q_gain = (const float*)d_in[5];

  char* wsb = (char*)d_ws;
  u16* wqkv = (u16*)wsb;  wsb += (size_t)1536 * 1024 * 2;   // fused QKV weights
  u16* wpq  = (u16*)wsb;  wsb += (size_t)1024 * 1024 * 2;
  u16* xb   = (u16*)wsb;  wsb += (size_t)kTok * kDim * 2;
  u16* qh   = (u16*)wsb;  wsb += (size_t)kTok * kDim * 2;
  u16* khb  = (u16*)wsb;  wsb += (size_t)kTok * kHKV * kD * 2;
  u16* vTb  = (u16*)wsb;  wsb += (size_t)kTok * kHKV * kD * 2;
  u16* yo   = (u16*)wsb;  wsb += (size_t)kTok * kDim * 2;
  float* vcmp = (float*)wsb; wsb += (size_t)kTok * kHKV * kD * 4;
  float2* ropetab = (float2*)wsb; wsb += (size_t)kT * 16 * sizeof(float2);

  // 1) fused prep: rope table + x->bf16 + all weight fake-quant
  prep_kernel<<<4736, 256, 0, stream>>>(x, w_q, w_k, w_v, w_proj,
                                        xb, wqkv, wpq, ropetab);

  // 2) QKV GEMM (128x64, BK=64, global_load_lds) + fused RMSNorm/RoPE epilogue
  gemm_qkv<<<dim3(24, 32), 256, 0, stream>>>(xb, wqkv, ropetab, q_gain,
                                             qh, khb, vTb, vcmp);

  // 3) paired MFMA flash attention + projection removal -> yo (bf16)
  attn_mfma<<<dim3(16, kH, 2), 256, 0, stream>>>(qh, khb, vTb, vcmp, yo);

  // 4) output projection (fp32 out, 128x64, BK=64, global_load_lds)
  gemm_out<<<dim3(16, 32), 256, 0, stream>>>(yo, wpq, (float*)d_out);
}